// Round 1
// baseline (5867.567 us; speedup 1.0000x reference)
//
#include <hip/hip_runtime.h>
#include <stdint.h>

typedef unsigned short u16;
typedef __attribute__((ext_vector_type(8))) short short8;
typedef __attribute__((ext_vector_type(4))) float fx4;

#define TB 512   // T
#define HD 512   // H
#define G3 1536  // 3*H

static __device__ __forceinline__ u16 f2bf(float f) {
  union { float f; uint32_t u; } v; v.f = f;
  return (u16)((v.u + 0x7fffu + ((v.u >> 16) & 1u)) >> 16);
}
static __device__ __forceinline__ float bf2f(u16 s) {
  union { uint32_t u; float f; } v; v.u = ((uint32_t)s) << 16;
  return v.f;
}
static __device__ __forceinline__ void gl_lds16(const void* g, void* l) {
  __builtin_amdgcn_global_load_lds(
      (const __attribute__((address_space(1))) uint32_t*)g,
      (__attribute__((address_space(3))) uint32_t*)l, 16, 0, 0);
}
static __device__ __forceinline__ float sigm(float x) { return 1.f / (1.f + __expf(-x)); }
static __device__ __forceinline__ float tanh_fast(float x) { return 1.f - 2.f / (__expf(2.f * x) + 1.f); }

// ---------------- prep: bf16 conversions + layouts ----------------
// WxcT: [3072 n][512 k]  (B^T layout for gx GEMM; n<1536 -> Wx_f, else Wx_b)
// WhP : [2 d][96 nt][16 kb][64 lane][8 j]  (pre-packed MFMA B-fragments)
// WdT : [512 n][1024 k]  (B^T layout for projection GEMM)
__global__ void prep_kernel(const float* Wx_f, const float* Wh_f, const float* Wx_b,
                            const float* Wh_b, const float* Wd,
                            u16* WxcT, u16* WhP, u16* WdT) {
  int tid = blockIdx.x * blockDim.x + threadIdx.x;
  int np = gridDim.x * blockDim.x;
  for (int i = tid; i < 3072 * 512; i += np) {
    int n = i >> 9, k = i & 511;
    float v = (n < G3) ? Wx_f[(size_t)k * G3 + n] : Wx_b[(size_t)k * G3 + (n - G3)];
    WxcT[i] = f2bf(v);
  }
  for (int i = tid; i < 2 * 96 * 16 * 512; i += np) {
    int jj = i & 7, lane = (i >> 3) & 63, kb = (i >> 9) & 15;
    int ntd = i >> 13;
    int nt = ntd % 96, d = ntd / 96;
    int n = nt * 16 + (lane & 15);
    int k = kb * 32 + (lane >> 4) * 8 + jj;
    const float* Wh = d ? Wh_b : Wh_f;
    WhP[i] = f2bf(Wh[(size_t)k * G3 + n]);
  }
  for (int i = tid; i < 512 * 1024; i += np) {
    int n = i >> 10, k = i & 1023;
    WdT[i] = f2bf(Wd[(size_t)k * 512 + n]);
  }
}

// ---------------- embedding gather-sum ----------------
__global__ void embed_kernel(const int* seqs, const float* emb, u16* embedded) {
  int r = blockIdx.x;       // b*T + t, 0..16383
  int tid = threadIdx.x;    // 128 threads
  const int* s = seqs + (size_t)r * 4;
  int c = tid * 4;
  float4 a = *(const float4*)(emb + (size_t)s[0] * HD + c);
  float4 b = *(const float4*)(emb + (size_t)s[1] * HD + c);
  float4 d = *(const float4*)(emb + (size_t)s[2] * HD + c);
  float4 e = *(const float4*)(emb + (size_t)s[3] * HD + c);
  float o0 = a.x + b.x + d.x + e.x;
  float o1 = a.y + b.y + d.y + e.y;
  float o2 = a.z + b.z + d.z + e.z;
  float o3 = a.w + b.w + d.w + e.w;
  uint2 uu;
  uu.x = (uint32_t)f2bf(o0) | ((uint32_t)f2bf(o1) << 16);
  uu.y = (uint32_t)f2bf(o2) | ((uint32_t)f2bf(o3) << 16);
  *(uint2*)(embedded + (size_t)r * HD + c) = uu;
}

// ---------------- gx = embedded @ [Wx_f | Wx_b] + b_in ----------------
// A: 16384x512 bf16, Bt: 3072x512 bf16 (B^T), C: 16384x3072 bf16
__launch_bounds__(256)
__global__ void gemm_gx(const u16* A, const u16* Bt, const float* b_f, const float* b_b, u16* C) {
  __shared__ u16 As[128 * 32];
  __shared__ u16 Bs[128 * 32];
  int tn = blockIdx.x, tm = blockIdx.y;
  int tid = threadIdx.x, wv = tid >> 6, lane = tid & 63;
  int wm = wv >> 1, wn = wv & 1;
  int l15 = lane & 15, q = lane >> 4;
  fx4 acc[4][4];
  for (int i = 0; i < 4; i++) for (int jn = 0; jn < 4; jn++) acc[i][jn] = (fx4){0.f, 0.f, 0.f, 0.f};
  for (int kk = 0; kk < 16; kk++) {
    for (int cc = 0; cc < 2; cc++) {
      int row = wv * 32 + cc * 16 + (lane >> 2);
      int seg = lane & 3;
      gl_lds16(A + (size_t)(tm * 128 + row) * 512 + kk * 32 + seg * 8,
               (char*)As + (wv * 32 + cc * 16) * 64);
      gl_lds16(Bt + (size_t)(tn * 128 + row) * 512 + kk * 32 + seg * 8,
               (char*)Bs + (wv * 32 + cc * 16) * 64);
    }
    __builtin_amdgcn_s_waitcnt(0);
    __syncthreads();
    short8 af[4], bfr[4];
    for (int mt = 0; mt < 4; mt++)
      af[mt] = *(const short8*)((const char*)As + (wm * 64 + mt * 16 + l15) * 64 + q * 16);
    for (int nt = 0; nt < 4; nt++)
      bfr[nt] = *(const short8*)((const char*)Bs + (wn * 64 + nt * 16 + l15) * 64 + q * 16);
    for (int mt = 0; mt < 4; mt++)
      for (int nt = 0; nt < 4; nt++)
        acc[mt][nt] = __builtin_amdgcn_mfma_f32_16x16x32_bf16(af[mt], bfr[nt], acc[mt][nt], 0, 0, 0);
    __syncthreads();
  }
  for (int nt = 0; nt < 4; nt++) {
    int col = tn * 128 + wn * 64 + nt * 16 + l15;
    float bias = (col < G3) ? b_f[col] : b_b[col - G3];
    for (int mt = 0; mt < 4; mt++)
      for (int rg = 0; rg < 4; rg++) {
        int row = tm * 128 + wm * 64 + mt * 16 + q * 4 + rg;
        C[(size_t)row * 3072 + col] = f2bf(acc[mt][nt][rg] + bias);
      }
  }
}

// ---------------- persistent bidirectional GRU ----------------
// 16 WGs: d = wg/8 (0 fwd, 1 bwd), isl = wg%8 owns h-cols [isl*64, isl*64+64).
// Wh B-fragments register-resident; per-step h-slice exchange via LLC atomics.
__launch_bounds__(512, 2)
__global__ void gru_kernel(const u16* gxAll, const u16* WhP, const float* b_f, const float* b_b,
                           u16* out_all, u16* hiddenA, uint32_t* hEx, int* flags) {
  __shared__ u16 hA[32 * 520];      // full h (bf16), row stride 520 (pad 8) -> conflict-free frags
  __shared__ float hOld[32 * 64];   // own slice, f32 master
  __shared__ float red[24 * 256];   // cross-wave K-half reduction
  __shared__ u16 gxs[32 * 192];     // staged gx slice for current t
  int wgid = blockIdx.x;
  int d = wgid >> 3, isl = wgid & 7;
  int tid = threadIdx.x;
  int wv = tid >> 6, lane = tid & 63;
  int a = wv & 3;      // n-tile quarter (16 h-cols)
  int jh = wv >> 2;    // K half (8 kblocks each)
  int l15 = lane & 15, q = lane >> 4;

  for (int i = tid; i < 32 * 520 / 2; i += 512) ((uint32_t*)hA)[i] = 0u;
  for (int i = tid; i < 2048; i += 512) hOld[i] = 0.f;

  short8 Bf[3][8];  // resident Wh fragments: 3 gates x 8 kblocks
  for (int g = 0; g < 3; g++) {
    int ntg = g * 32 + isl * 4 + a;
    for (int kk = 0; kk < 8; kk++) {
      int kb = jh * 8 + kk;
      Bf[g][kk] = *(const short8*)(WhP + ((((size_t)d * 96 + ntg) * 16 + kb) * 64 + lane) * 8);
    }
  }
  const float* bias = d ? b_b : b_f;
  int cloc = a * 16 + l15;   // col in own 64-slice
  int gc = isl * 64 + cloc;  // global h-col
  float brz = bias[G3 + gc];
  float brr = bias[G3 + 512 + gc];
  float brn = bias[G3 + 1024 + gc];

  __syncthreads();

  for (int s = 0; s < TB; s++) {
    int t = d ? (TB - 1 - s) : s;
    {  // stage gx slice (32 b x 192 cols bf16)
      const uint32_t* gxu = (const uint32_t*)gxAll;
      uint32_t* gxsu = (uint32_t*)gxs;
      for (int idx = tid; idx < 3072; idx += 512) {
        int b = idx / 96, u = idx - b * 96;
        int g = u >> 5, c2 = u & 31;
        gxsu[b * 96 + u] = gxu[((size_t)b * TB + t) * 1536 + d * 768 + g * 256 + isl * 32 + c2];
      }
    }
    fx4 acc[2][3];
    for (int mt = 0; mt < 2; mt++) for (int g = 0; g < 3; g++) acc[mt][g] = (fx4){0.f, 0.f, 0.f, 0.f};
    for (int mt = 0; mt < 2; mt++) {
      short8 Af[8];
      for (int kk = 0; kk < 8; kk++) {
        int kb = jh * 8 + kk;
        Af[kk] = *(const short8*)((const char*)hA + (mt * 16 + l15) * 1040 + kb * 64 + q * 16);
      }
      for (int g = 0; g < 3; g++)
        for (int kk = 0; kk < 8; kk++)
          acc[mt][g] = __builtin_amdgcn_mfma_f32_16x16x32_bf16(Af[kk], Bf[g][kk], acc[mt][g], 0, 0, 0);
    }
    if (jh == 1) {
      for (int mt = 0; mt < 2; mt++)
        for (int g = 0; g < 3; g++) {
          float* tp = red + ((a * 2 + mt) * 3 + g) * 256;
          for (int rg = 0; rg < 4; rg++) tp[(q * 4 + rg) * 16 + l15] = acc[mt][g][rg];
        }
    }
    __syncthreads();
    if (jh == 0) {  // reduce + pointwise GRU cell
      for (int mt = 0; mt < 2; mt++) {
        const float* tpz = red + ((a * 2 + mt) * 3 + 0) * 256;
        const float* tpr = red + ((a * 2 + mt) * 3 + 1) * 256;
        const float* tpn = red + ((a * 2 + mt) * 3 + 2) * 256;
        for (int rg = 0; rg < 4; rg++) {
          int b = mt * 16 + q * 4 + rg;
          int fi = (q * 4 + rg) * 16 + l15;
          float ghz = acc[mt][0][rg] + tpz[fi] + brz;
          float ghr = acc[mt][1][rg] + tpr[fi] + brr;
          float ghn = acc[mt][2][rg] + tpn[fi] + brn;
          float gxz = bf2f(gxs[b * 192 + cloc]);
          float gxr = bf2f(gxs[b * 192 + 64 + cloc]);
          float gxn = bf2f(gxs[b * 192 + 128 + cloc]);
          float z = sigm(gxz + ghz);
          float rr = sigm(gxr + ghr);
          float hc = tanh_fast(gxn + rr * ghn);
          float hp = hOld[b * 64 + cloc];
          float hnw = z * hp + (1.f - z) * hc;
          hOld[b * 64 + cloc] = hnw;
          u16 hb = f2bf(hnw);
          *((u16*)hA + b * 520 + gc) = hb;
          out_all[((size_t)b * TB + t) * 1024 + d * 512 + gc] = hb;
          if (s == TB - 1) hiddenA[(size_t)b * 1024 + d * 512 + gc] = hb;
        }
      }
    }
    __syncthreads();
    {  // publish own slice to LLC (parity double-buffer)
      int p = (s + 1) & 1;
      uint32_t* dst = hEx + ((size_t)(d * 2 + p) * 8 + isl) * 1024;
      for (int idx = tid; idx < 1024; idx += 512) {
        int m = idx >> 5, u = idx & 31;
        uint32_t v = *(const uint32_t*)((const char*)hA + m * 1040 + isl * 128 + u * 4);
        __hip_atomic_store(&dst[idx], v, __ATOMIC_RELAXED, __HIP_MEMORY_SCOPE_AGENT);
      }
    }
    __syncthreads();
    if (tid == 0) __hip_atomic_store(&flags[wgid], s + 1, __ATOMIC_RELEASE, __HIP_MEMORY_SCOPE_AGENT);
    if (s == TB - 1) break;
    if (tid < 8 && tid != isl) {  // bounded spin on peers
      int peer = d * 8 + tid;
      long long spins = 0;
      while (__hip_atomic_load(&flags[peer], __ATOMIC_RELAXED, __HIP_MEMORY_SCOPE_AGENT) < s + 1) {
        if (++spins > 200000000LL) break;
      }
    }
    __syncthreads();
    __builtin_amdgcn_fence(__ATOMIC_ACQUIRE, "agent");
    {  // gather peer slices into hA
      int p = (s + 1) & 1;
      for (int pj = 0; pj < 8; pj++) {
        if (pj == isl) continue;
        const uint32_t* src = hEx + ((size_t)(d * 2 + p) * 8 + pj) * 1024;
        for (int idx = tid; idx < 1024; idx += 512) {
          uint32_t v = __hip_atomic_load(&src[idx], __ATOMIC_RELAXED, __HIP_MEMORY_SCOPE_AGENT);
          int m = idx >> 5, u = idx & 31;
          *(uint32_t*)((char*)hA + m * 1040 + pj * 128 + u * 4) = v;
        }
      }
    }
    __syncthreads();
  }
}

// ---------------- projection: [out_f|out_b] @ Wd + bd ----------------
__launch_bounds__(256)
__global__ void gemm_proj(const u16* Aall, const u16* hiddenA, const u16* WdT,
                          const float* bd, float* out) {
  __shared__ u16 As[128 * 32];
  __shared__ u16 Bs[128 * 32];
  int tn = blockIdx.x, tm = blockIdx.y;  // tn 0..3, tm 0..128 (128 == hidden tile)
  const u16* A = (tm < 128) ? (Aall + (size_t)tm * 128 * 1024) : hiddenA;
  int tid = threadIdx.x, wv = tid >> 6, lane = tid & 63;
  int wm = wv >> 1, wn = wv & 1;
  int l15 = lane & 15, q = lane >> 4;
  fx4 acc[4][4];
  for (int i = 0; i < 4; i++) for (int jn = 0; jn < 4; jn++) acc[i][jn] = (fx4){0.f, 0.f, 0.f, 0.f};
  for (int kk = 0; kk < 32; kk++) {
    for (int cc = 0; cc < 2; cc++) {
      int row = wv * 32 + cc * 16 + (lane >> 2);
      int seg = lane & 3;
      gl_lds16(A + (size_t)row * 1024 + kk * 32 + seg * 8,
               (char*)As + (wv * 32 + cc * 16) * 64);
      gl_lds16(WdT + (size_t)(tn * 128 + row) * 1024 + kk * 32 + seg * 8,
               (char*)Bs + (wv * 32 + cc * 16) * 64);
    }
    __builtin_amdgcn_s_waitcnt(0);
    __syncthreads();
    short8 af[4], bfr[4];
    for (int mt = 0; mt < 4; mt++)
      af[mt] = *(const short8*)((const char*)As + (wm * 64 + mt * 16 + l15) * 64 + q * 16);
    for (int nt = 0; nt < 4; nt++)
      bfr[nt] = *(const short8*)((const char*)Bs + (wn * 64 + nt * 16 + l15) * 64 + q * 16);
    for (int mt = 0; mt < 4; mt++)
      for (int nt = 0; nt < 4; nt++)
        acc[mt][nt] = __builtin_amdgcn_mfma_f32_16x16x32_bf16(af[mt], bfr[nt], acc[mt][nt], 0, 0, 0);
    __syncthreads();
  }
  for (int nt = 0; nt < 4; nt++) {
    int col = tn * 128 + wn * 64 + nt * 16 + l15;
    float bias = bd[col];
    for (int mt = 0; mt < 4; mt++)
      for (int rg = 0; rg < 4; rg++) {
        int row = wm * 64 + mt * 16 + q * 4 + rg;
        float v = acc[mt][nt][rg] + bias;
        if (tm < 128) out[((size_t)tm * 128 + row) * 512 + col] = v;
        else if (row < 32) out[(size_t)16384 * 512 + (size_t)row * 512 + col] = v;
      }
  }
}

extern "C" void kernel_launch(void* const* d_in, const int* in_sizes, int n_in,
                              void* d_out, int out_size, void* d_ws, size_t ws_size,
                              hipStream_t stream) {
  (void)in_sizes; (void)n_in; (void)out_size; (void)ws_size;
  const int* seqs = (const int*)d_in[0];
  const float* emb = (const float*)d_in[2];
  const float* Wx_f = (const float*)d_in[3];
  const float* Wh_f = (const float*)d_in[4];
  const float* b_f = (const float*)d_in[5];
  const float* Wx_b = (const float*)d_in[6];
  const float* Wh_b = (const float*)d_in[7];
  const float* b_b = (const float*)d_in[8];
  const float* Wd = (const float*)d_in[9];
  const float* bd = (const float*)d_in[10];
  char* ws = (char*)d_ws;
  u16* WxcT     = (u16*)(ws + 0);            // 3,145,728 B
  u16* WhP      = (u16*)(ws + 3145728);      // 3,145,728 B
  u16* WdT      = (u16*)(ws + 6291456);      // 1,048,576 B
  u16* embedded = (u16*)(ws + 7340032);      // 16,777,216 B
  u16* gxAll    = (u16*)(ws + 24117248);     // 100,663,296 B
  u16* out_all  = (u16*)(ws + 124780544);    // 33,554,432 B
  u16* hiddenA  = (u16*)(ws + 158334976);    // 262,144 B (rows 32..127 unused)
  uint32_t* hEx = (uint32_t*)(ws + 158597120); // 131,072 B
  int* flags    = (int*)(ws + 158728192);    // 64 B

  hipMemsetAsync(flags, 0, 64, stream);
  prep_kernel<<<512, 256, 0, stream>>>(Wx_f, Wh_f, Wx_b, Wh_b, Wd, WxcT, WhP, WdT);
  embed_kernel<<<16384, 128, 0, stream>>>(seqs, emb, embedded);
  gemm_gx<<<dim3(24, 128), 256, 0, stream>>>(embedded, WxcT, b_f, b_b, gxAll);
  gru_kernel<<<16, 512, 0, stream>>>(gxAll, WhP, b_f, b_b, out_all, hiddenA, hEx, flags);
  gemm_proj<<<dim3(4, 129), 256, 0, stream>>>(out_all, hiddenA, WdT, bd, (float*)d_out);
}

// Round 2
// 5677.712 us; speedup vs baseline: 1.0334x; 1.0334x over previous
//
#include <hip/hip_runtime.h>
#include <stdint.h>

typedef unsigned short u16;
typedef __attribute__((ext_vector_type(8))) short short8;
typedef __attribute__((ext_vector_type(4))) float fx4;

#define TB 512   // T
#define HD 512   // H
#define G3 1536  // 3*H

static __device__ __forceinline__ u16 f2bf(float f) {
  union { float f; uint32_t u; } v; v.f = f;
  return (u16)((v.u + 0x7fffu + ((v.u >> 16) & 1u)) >> 16);
}
static __device__ __forceinline__ float bf2f(u16 s) {
  union { uint32_t u; float f; } v; v.u = ((uint32_t)s) << 16;
  return v.f;
}
static __device__ __forceinline__ void gl_lds16(const void* g, void* l) {
  __builtin_amdgcn_global_load_lds(
      (const __attribute__((address_space(1))) uint32_t*)g,
      (__attribute__((address_space(3))) uint32_t*)l, 16, 0, 0);
}
static __device__ __forceinline__ float sigm(float x) { return 1.f / (1.f + __expf(-x)); }
static __device__ __forceinline__ float tanh_fast(float x) { return 1.f - 2.f / (__expf(2.f * x) + 1.f); }

// ---------------- prep: bf16 conversions + layouts ----------------
__global__ void prep_kernel(const float* Wx_f, const float* Wh_f, const float* Wx_b,
                            const float* Wh_b, const float* Wd,
                            u16* WxcT, u16* WhP, u16* WdT) {
  int tid = blockIdx.x * blockDim.x + threadIdx.x;
  int np = gridDim.x * blockDim.x;
  for (int i = tid; i < 3072 * 512; i += np) {
    int n = i >> 9, k = i & 511;
    float v = (n < G3) ? Wx_f[(size_t)k * G3 + n] : Wx_b[(size_t)k * G3 + (n - G3)];
    WxcT[i] = f2bf(v);
  }
  for (int i = tid; i < 2 * 96 * 16 * 512; i += np) {
    int jj = i & 7, lane = (i >> 3) & 63, kb = (i >> 9) & 15;
    int ntd = i >> 13;
    int nt = ntd % 96, d = ntd / 96;
    int n = nt * 16 + (lane & 15);
    int k = kb * 32 + (lane >> 4) * 8 + jj;
    const float* Wh = d ? Wh_b : Wh_f;
    WhP[i] = f2bf(Wh[(size_t)k * G3 + n]);
  }
  for (int i = tid; i < 512 * 1024; i += np) {
    int n = i >> 10, k = i & 1023;
    WdT[i] = f2bf(Wd[(size_t)k * 512 + n]);
  }
}

// ---------------- embedding gather-sum ----------------
__global__ void embed_kernel(const int* seqs, const float* emb, u16* embedded) {
  int r = blockIdx.x;
  int tid = threadIdx.x;
  const int* s = seqs + (size_t)r * 4;
  int c = tid * 4;
  float4 a = *(const float4*)(emb + (size_t)s[0] * HD + c);
  float4 b = *(const float4*)(emb + (size_t)s[1] * HD + c);
  float4 d = *(const float4*)(emb + (size_t)s[2] * HD + c);
  float4 e = *(const float4*)(emb + (size_t)s[3] * HD + c);
  float o0 = a.x + b.x + d.x + e.x;
  float o1 = a.y + b.y + d.y + e.y;
  float o2 = a.z + b.z + d.z + e.z;
  float o3 = a.w + b.w + d.w + e.w;
  uint2 uu;
  uu.x = (uint32_t)f2bf(o0) | ((uint32_t)f2bf(o1) << 16);
  uu.y = (uint32_t)f2bf(o2) | ((uint32_t)f2bf(o3) << 16);
  *(uint2*)(embedded + (size_t)r * HD + c) = uu;
}

// ---------------- gx = embedded @ [Wx_f | Wx_b] + b_in ----------------
__launch_bounds__(256)
__global__ void gemm_gx(const u16* A, const u16* Bt, const float* b_f, const float* b_b, u16* C) {
  __shared__ u16 As[128 * 32];
  __shared__ u16 Bs[128 * 32];
  int tn = blockIdx.x, tm = blockIdx.y;
  int tid = threadIdx.x, wv = tid >> 6, lane = tid & 63;
  int wm = wv >> 1, wn = wv & 1;
  int l15 = lane & 15, q = lane >> 4;
  fx4 acc[4][4];
  for (int i = 0; i < 4; i++) for (int jn = 0; jn < 4; jn++) acc[i][jn] = (fx4){0.f, 0.f, 0.f, 0.f};
  for (int kk = 0; kk < 16; kk++) {
    for (int cc = 0; cc < 2; cc++) {
      int row = wv * 32 + cc * 16 + (lane >> 2);
      int seg = lane & 3;
      gl_lds16(A + (size_t)(tm * 128 + row) * 512 + kk * 32 + seg * 8,
               (char*)As + (wv * 32 + cc * 16) * 64);
      gl_lds16(Bt + (size_t)(tn * 128 + row) * 512 + kk * 32 + seg * 8,
               (char*)Bs + (wv * 32 + cc * 16) * 64);
    }
    __builtin_amdgcn_s_waitcnt(0);
    __syncthreads();
    short8 af[4], bfr[4];
    for (int mt = 0; mt < 4; mt++)
      af[mt] = *(const short8*)((const char*)As + (wm * 64 + mt * 16 + l15) * 64 + q * 16);
    for (int nt = 0; nt < 4; nt++)
      bfr[nt] = *(const short8*)((const char*)Bs + (wn * 64 + nt * 16 + l15) * 64 + q * 16);
    for (int mt = 0; mt < 4; mt++)
      for (int nt = 0; nt < 4; nt++)
        acc[mt][nt] = __builtin_amdgcn_mfma_f32_16x16x32_bf16(af[mt], bfr[nt], acc[mt][nt], 0, 0, 0);
    __syncthreads();
  }
  for (int nt = 0; nt < 4; nt++) {
    int col = tn * 128 + wn * 64 + nt * 16 + l15;
    float bias = (col < G3) ? b_f[col] : b_b[col - G3];
    for (int mt = 0; mt < 4; mt++)
      for (int rg = 0; rg < 4; rg++) {
        int row = tm * 128 + wm * 64 + mt * 16 + q * 4 + rg;
        C[(size_t)row * 3072 + col] = f2bf(acc[mt][nt][rg] + bias);
      }
  }
}

// ---------------- persistent bidirectional GRU ----------------
// 16 WGs: d = wg/8, isl = wg%8 owns h-cols [isl*64, isl*64+64).
// Cross-WG h exchange: relaxed AGENT atomics only (LLC-coherent, no cache
// maintenance). 2 barriers/step. gx staged via double-buffered global_load_lds.
__launch_bounds__(512, 2)
__global__ void gru_kernel(const u16* gxAll, const u16* WhP, const float* b_f, const float* b_b,
                           u16* out_all, u16* hiddenA, uint32_t* hEx, int* flags) {
  __shared__ u16 hA[32 * 520];      // full h (bf16), row stride 520
  __shared__ float hOld[32 * 64];   // own slice, f32 master
  __shared__ float red[24 * 256];   // cross-wave K-half reduction
  __shared__ u16 gxs[2][32 * 192];  // double-buffered gx slice, layout [b][g][64]
  int wgid = blockIdx.x;
  int d = wgid >> 3, isl = wgid & 7;
  int tid = threadIdx.x;
  int wv = tid >> 6, lane = tid & 63;
  int a = wv & 3;      // n-tile quarter (16 h-cols)
  int jh = wv >> 2;    // K half
  int l15 = lane & 15, q = lane >> 4;

  for (int i = tid; i < 32 * 520 / 2; i += 512) ((uint32_t*)hA)[i] = 0u;
  for (int i = tid; i < 2048; i += 512) hOld[i] = 0.f;

  short8 Bf[3][8];
  for (int g = 0; g < 3; g++) {
    int ntg = g * 32 + isl * 4 + a;
    for (int kk = 0; kk < 8; kk++) {
      int kb = jh * 8 + kk;
      Bf[g][kk] = *(const short8*)(WhP + ((((size_t)d * 96 + ntg) * 16 + kb) * 64 + lane) * 8);
    }
  }
  const float* bias = d ? b_b : b_f;
  int cloc = a * 16 + l15;
  int gc = isl * 64 + cloc;
  float brz = bias[G3 + gc];
  float brr = bias[G3 + 512 + gc];
  float brn = bias[G3 + 1024 + gc];

  // prologue: stage gx for t(0) into buffer 0 (all waves)
  {
    int t0 = d ? (TB - 1) : 0;
    for (int it = wv; it < 12; it += 8) {
      int slot = it * 64 + lane;
      int chunk = slot >> 3, sub = slot & 7;
      int b = chunk / 3, g = chunk - b * 3;
      gl_lds16(gxAll + (size_t)(b * TB + t0) * 3072 + d * 1536 + g * 512 + isl * 64 + sub * 8,
               (char*)gxs[0] + it * 1024);
    }
  }
  __builtin_amdgcn_s_waitcnt(0);
  __syncthreads();

  for (int s = 0; s < TB; s++) {
    int t = d ? (TB - 1 - s) : s;
    // ---- phase A: prefetch gx(s+1), MFMA h@Wh, write cross-K partials ----
    if (jh == 0 && s + 1 < TB) {
      int t1 = d ? (TB - 2 - s) : (s + 1);
      char* dst = (char*)gxs[(s + 1) & 1];
      for (int it = a; it < 12; it += 4) {
        int slot = it * 64 + lane;
        int chunk = slot >> 3, sub = slot & 7;
        int b = chunk / 3, g = chunk - b * 3;
        gl_lds16(gxAll + (size_t)(b * TB + t1) * 3072 + d * 1536 + g * 512 + isl * 64 + sub * 8,
                 dst + it * 1024);
      }
    }
    fx4 acc[2][3];
    for (int mt = 0; mt < 2; mt++) for (int g = 0; g < 3; g++) acc[mt][g] = (fx4){0.f, 0.f, 0.f, 0.f};
    for (int mt = 0; mt < 2; mt++) {
      short8 Af[8];
      for (int kk = 0; kk < 8; kk++) {
        int kb = jh * 8 + kk;
        Af[kk] = *(const short8*)((const char*)hA + (mt * 16 + l15) * 1040 + kb * 64 + q * 16);
      }
      for (int g = 0; g < 3; g++)
        for (int kk = 0; kk < 8; kk++)
          acc[mt][g] = __builtin_amdgcn_mfma_f32_16x16x32_bf16(Af[kk], Bf[g][kk], acc[mt][g], 0, 0, 0);
    }
    if (jh == 1) {
      for (int mt = 0; mt < 2; mt++)
        for (int g = 0; g < 3; g++) {
          float* tp = red + ((a * 2 + mt) * 3 + g) * 256;
          for (int rg = 0; rg < 4; rg++) tp[(q * 4 + rg) * 16 + l15] = acc[mt][g][rg];
        }
    }
    __syncthreads();  // barrier 1

    // ---- phase B: cell+publish+flag (jh==0) || poll+gather (waves 1..7) ----
    if (jh == 0) {
      const u16* gxc = gxs[s & 1];
      u16 hv[2][4];
      for (int mt = 0; mt < 2; mt++) {
        const float* tpz = red + ((a * 2 + mt) * 3 + 0) * 256;
        const float* tpr = red + ((a * 2 + mt) * 3 + 1) * 256;
        const float* tpn = red + ((a * 2 + mt) * 3 + 2) * 256;
        for (int rg = 0; rg < 4; rg++) {
          int b = mt * 16 + q * 4 + rg;
          int fi = (q * 4 + rg) * 16 + l15;
          float ghz = acc[mt][0][rg] + tpz[fi] + brz;
          float ghr = acc[mt][1][rg] + tpr[fi] + brr;
          float ghn = acc[mt][2][rg] + tpn[fi] + brn;
          float gxz = bf2f(gxc[b * 192 + cloc]);
          float gxr = bf2f(gxc[b * 192 + 64 + cloc]);
          float gxn = bf2f(gxc[b * 192 + 128 + cloc]);
          float z = sigm(gxz + ghz);
          float rr = sigm(gxr + ghr);
          float hc = tanh_fast(gxn + rr * ghn);
          float hp = hOld[b * 64 + cloc];
          float hnw = z * hp + (1.f - z) * hc;
          hOld[b * 64 + cloc] = hnw;
          u16 hb = f2bf(hnw);
          hv[mt][rg] = hb;
          hA[b * 520 + gc] = hb;
          out_all[((size_t)b * TB + t) * 1024 + d * 512 + gc] = hb;
          if (s == TB - 1) hiddenA[(size_t)b * 1024 + d * 512 + gc] = hb;
        }
      }
      if (s < TB - 1) {
        int p = (s + 1) & 1;
        uint32_t* slot = hEx + ((size_t)(d * 2 + p) * 8 + isl) * 1024;
        for (int mt = 0; mt < 2; mt++)
          for (int pr = 0; pr < 2; pr++) {
            uint32_t pk = (uint32_t)hv[mt][2 * pr] | ((uint32_t)hv[mt][2 * pr + 1] << 16);
            __hip_atomic_store(&slot[cloc * 16 + mt * 8 + q * 2 + pr], pk,
                               __ATOMIC_RELAXED, __HIP_MEMORY_SCOPE_AGENT);
          }
      }
      __builtin_amdgcn_s_waitcnt(0);  // drain publish + prefetch + out_all
      __builtin_amdgcn_fence(__ATOMIC_RELEASE, "workgroup");  // compiler ordering, no cache ops
      if (s < TB - 1 && lane == 0)
        __hip_atomic_fetch_add(&flags[wgid], 1, __ATOMIC_RELAXED, __HIP_MEMORY_SCOPE_AGENT);
    }
    if (s == TB - 1) break;
    if (wv >= 1) {  // gather one peer slice per wave
      int pj = (isl + wv) & 7;
      int peer = d * 8 + pj;
      int target = 4 * (s + 1);
      long long spins = 0;
      while (__hip_atomic_load(&flags[peer], __ATOMIC_RELAXED, __HIP_MEMORY_SCOPE_AGENT) < target) {
        if (++spins > (1LL << 40)) break;
      }
      __builtin_amdgcn_fence(__ATOMIC_ACQUIRE, "workgroup");
      const uint32_t* src = hEx + ((size_t)(d * 2 + ((s + 1) & 1)) * 8 + pj) * 1024 + lane * 16;
      uint32_t v[16];
      for (int k = 0; k < 16; k++)
        v[k] = __hip_atomic_load(&src[k], __ATOMIC_RELAXED, __HIP_MEMORY_SCOPE_AGENT);
      for (int k = 0; k < 16; k++) {
        int mt = k >> 3, rem = k & 7;
        int row0 = mt * 16 + (rem >> 1) * 4 + (rem & 1) * 2;
        hA[row0 * 520 + pj * 64 + lane] = (u16)(v[k] & 0xffffu);
        hA[(row0 + 1) * 520 + pj * 64 + lane] = (u16)(v[k] >> 16);
      }
    }
    __syncthreads();  // barrier 2
  }
}

// ---------------- projection: [out_f|out_b] @ Wd + bd ----------------
__launch_bounds__(256)
__global__ void gemm_proj(const u16* Aall, const u16* hiddenA, const u16* WdT,
                          const float* bd, float* out) {
  __shared__ u16 As[128 * 32];
  __shared__ u16 Bs[128 * 32];
  int tn = blockIdx.x, tm = blockIdx.y;
  const u16* A = (tm < 128) ? (Aall + (size_t)tm * 128 * 1024) : hiddenA;
  int tid = threadIdx.x, wv = tid >> 6, lane = tid & 63;
  int wm = wv >> 1, wn = wv & 1;
  int l15 = lane & 15, q = lane >> 4;
  fx4 acc[4][4];
  for (int i = 0; i < 4; i++) for (int jn = 0; jn < 4; jn++) acc[i][jn] = (fx4){0.f, 0.f, 0.f, 0.f};
  for (int kk = 0; kk < 32; kk++) {
    for (int cc = 0; cc < 2; cc++) {
      int row = wv * 32 + cc * 16 + (lane >> 2);
      int seg = lane & 3;
      gl_lds16(A + (size_t)row * 1024 + kk * 32 + seg * 8,
               (char*)As + (wv * 32 + cc * 16) * 64);
      gl_lds16(WdT + (size_t)(tn * 128 + row) * 1024 + kk * 32 + seg * 8,
               (char*)Bs + (wv * 32 + cc * 16) * 64);
    }
    __builtin_amdgcn_s_waitcnt(0);
    __syncthreads();
    short8 af[4], bfr[4];
    for (int mt = 0; mt < 4; mt++)
      af[mt] = *(const short8*)((const char*)As + (wm * 64 + mt * 16 + l15) * 64 + q * 16);
    for (int nt = 0; nt < 4; nt++)
      bfr[nt] = *(const short8*)((const char*)Bs + (wn * 64 + nt * 16 + l15) * 64 + q * 16);
    for (int mt = 0; mt < 4; mt++)
      for (int nt = 0; nt < 4; nt++)
        acc[mt][nt] = __builtin_amdgcn_mfma_f32_16x16x32_bf16(af[mt], bfr[nt], acc[mt][nt], 0, 0, 0);
    __syncthreads();
  }
  for (int nt = 0; nt < 4; nt++) {
    int col = tn * 128 + wn * 64 + nt * 16 + l15;
    float bias = bd[col];
    for (int mt = 0; mt < 4; mt++)
      for (int rg = 0; rg < 4; rg++) {
        int row = wm * 64 + mt * 16 + q * 4 + rg;
        float v = acc[mt][nt][rg] + bias;
        if (tm < 128) out[((size_t)tm * 128 + row) * 512 + col] = v;
        else if (row < 32) out[(size_t)16384 * 512 + (size_t)row * 512 + col] = v;
      }
  }
}

extern "C" void kernel_launch(void* const* d_in, const int* in_sizes, int n_in,
                              void* d_out, int out_size, void* d_ws, size_t ws_size,
                              hipStream_t stream) {
  (void)in_sizes; (void)n_in; (void)out_size; (void)ws_size;
  const int* seqs = (const int*)d_in[0];
  const float* emb = (const float*)d_in[2];
  const float* Wx_f = (const float*)d_in[3];
  const float* Wh_f = (const float*)d_in[4];
  const float* b_f = (const float*)d_in[5];
  const float* Wx_b = (const float*)d_in[6];
  const float* Wh_b = (const float*)d_in[7];
  const float* b_b = (const float*)d_in[8];
  const float* Wd = (const float*)d_in[9];
  const float* bd = (const float*)d_in[10];
  char* ws = (char*)d_ws;
  u16* WxcT     = (u16*)(ws + 0);
  u16* WhP      = (u16*)(ws + 3145728);
  u16* WdT      = (u16*)(ws + 6291456);
  u16* embedded = (u16*)(ws + 7340032);
  u16* gxAll    = (u16*)(ws + 24117248);
  u16* out_all  = (u16*)(ws + 124780544);
  u16* hiddenA  = (u16*)(ws + 158334976);
  uint32_t* hEx = (uint32_t*)(ws + 158597120);
  int* flags    = (int*)(ws + 158728192);

  hipMemsetAsync(flags, 0, 64, stream);
  prep_kernel<<<512, 256, 0, stream>>>(Wx_f, Wh_f, Wx_b, Wh_b, Wd, WxcT, WhP, WdT);
  embed_kernel<<<16384, 128, 0, stream>>>(seqs, emb, embedded);
  gemm_gx<<<dim3(24, 128), 256, 0, stream>>>(embedded, WxcT, b_f, b_b, gxAll);
  gru_kernel<<<16, 512, 0, stream>>>(gxAll, WhP, b_f, b_b, out_all, hiddenA, hEx, flags);
  gemm_proj<<<dim3(4, 129), 256, 0, stream>>>(out_all, hiddenA, WdT, bd, (float*)d_out);
}

// Round 3
// 4001.260 us; speedup vs baseline: 1.4664x; 1.4190x over previous
//
#include <hip/hip_runtime.h>
#include <stdint.h>

typedef unsigned short u16;
typedef __attribute__((ext_vector_type(8))) short short8;
typedef __attribute__((ext_vector_type(4))) float fx4;

#define TB 512   // T
#define HD 512   // H
#define G3 1536  // 3*H

static __device__ __forceinline__ u16 f2bf(float f) {
  union { float f; uint32_t u; } v; v.f = f;
  return (u16)((v.u + 0x7fffu + ((v.u >> 16) & 1u)) >> 16);
}
static __device__ __forceinline__ float bf2f(u16 s) {
  union { uint32_t u; float f; } v; v.u = ((uint32_t)s) << 16;
  return v.f;
}
static __device__ __forceinline__ void gl_lds16(const void* g, void* l) {
  __builtin_amdgcn_global_load_lds(
      (const __attribute__((address_space(1))) uint32_t*)g,
      (__attribute__((address_space(3))) uint32_t*)l, 16, 0, 0);
}
static __device__ __forceinline__ float sigm(float x) { return 1.f / (1.f + __expf(-x)); }
static __device__ __forceinline__ float tanh_fast(float x) { return 1.f - 2.f / (__expf(2.f * x) + 1.f); }

// ---------------- prep: bf16 conversions + layouts ----------------
__global__ void prep_kernel(const float* Wx_f, const float* Wh_f, const float* Wx_b,
                            const float* Wh_b, const float* Wd,
                            u16* WxcT, u16* WhP, u16* WdT) {
  int tid = blockIdx.x * blockDim.x + threadIdx.x;
  int np = gridDim.x * blockDim.x;
  for (int i = tid; i < 3072 * 512; i += np) {
    int n = i >> 9, k = i & 511;
    float v = (n < G3) ? Wx_f[(size_t)k * G3 + n] : Wx_b[(size_t)k * G3 + (n - G3)];
    WxcT[i] = f2bf(v);
  }
  for (int i = tid; i < 2 * 96 * 16 * 512; i += np) {
    int jj = i & 7, lane = (i >> 3) & 63, kb = (i >> 9) & 15;
    int ntd = i >> 13;
    int nt = ntd % 96, d = ntd / 96;
    int n = nt * 16 + (lane & 15);
    int k = kb * 32 + (lane >> 4) * 8 + jj;
    const float* Wh = d ? Wh_b : Wh_f;
    WhP[i] = f2bf(Wh[(size_t)k * G3 + n]);
  }
  for (int i = tid; i < 512 * 1024; i += np) {
    int n = i >> 10, k = i & 1023;
    WdT[i] = f2bf(Wd[(size_t)k * 512 + n]);
  }
}

// ---------------- embedding gather-sum ----------------
__global__ void embed_kernel(const int* seqs, const float* emb, u16* embedded) {
  int r = blockIdx.x;
  int tid = threadIdx.x;
  const int* s = seqs + (size_t)r * 4;
  int c = tid * 4;
  float4 a = *(const float4*)(emb + (size_t)s[0] * HD + c);
  float4 b = *(const float4*)(emb + (size_t)s[1] * HD + c);
  float4 d = *(const float4*)(emb + (size_t)s[2] * HD + c);
  float4 e = *(const float4*)(emb + (size_t)s[3] * HD + c);
  float o0 = a.x + b.x + d.x + e.x;
  float o1 = a.y + b.y + d.y + e.y;
  float o2 = a.z + b.z + d.z + e.z;
  float o3 = a.w + b.w + d.w + e.w;
  uint2 uu;
  uu.x = (uint32_t)f2bf(o0) | ((uint32_t)f2bf(o1) << 16);
  uu.y = (uint32_t)f2bf(o2) | ((uint32_t)f2bf(o3) << 16);
  *(uint2*)(embedded + (size_t)r * HD + c) = uu;
}

// ---------------- gx = embedded @ [Wx_f | Wx_b] + b_in ----------------
__launch_bounds__(256)
__global__ void gemm_gx(const u16* A, const u16* Bt, const float* b_f, const float* b_b, u16* C) {
  __shared__ u16 As[128 * 32];
  __shared__ u16 Bs[128 * 32];
  int tn = blockIdx.x, tm = blockIdx.y;
  int tid = threadIdx.x, wv = tid >> 6, lane = tid & 63;
  int wm = wv >> 1, wn = wv & 1;
  int l15 = lane & 15, q = lane >> 4;
  fx4 acc[4][4];
  for (int i = 0; i < 4; i++) for (int jn = 0; jn < 4; jn++) acc[i][jn] = (fx4){0.f, 0.f, 0.f, 0.f};
  for (int kk = 0; kk < 16; kk++) {
    for (int cc = 0; cc < 2; cc++) {
      int row = wv * 32 + cc * 16 + (lane >> 2);
      int seg = lane & 3;
      gl_lds16(A + (size_t)(tm * 128 + row) * 512 + kk * 32 + seg * 8,
               (char*)As + (wv * 32 + cc * 16) * 64);
      gl_lds16(Bt + (size_t)(tn * 128 + row) * 512 + kk * 32 + seg * 8,
               (char*)Bs + (wv * 32 + cc * 16) * 64);
    }
    __builtin_amdgcn_s_waitcnt(0);
    __syncthreads();
    short8 af[4], bfr[4];
    for (int mt = 0; mt < 4; mt++)
      af[mt] = *(const short8*)((const char*)As + (wm * 64 + mt * 16 + l15) * 64 + q * 16);
    for (int nt = 0; nt < 4; nt++)
      bfr[nt] = *(const short8*)((const char*)Bs + (wn * 64 + nt * 16 + l15) * 64 + q * 16);
    for (int mt = 0; mt < 4; mt++)
      for (int nt = 0; nt < 4; nt++)
        acc[mt][nt] = __builtin_amdgcn_mfma_f32_16x16x32_bf16(af[mt], bfr[nt], acc[mt][nt], 0, 0, 0);
    __syncthreads();
  }
  for (int nt = 0; nt < 4; nt++) {
    int col = tn * 128 + wn * 64 + nt * 16 + l15;
    float bias = (col < G3) ? b_f[col] : b_b[col - G3];
    for (int mt = 0; mt < 4; mt++)
      for (int rg = 0; rg < 4; rg++) {
        int row = tm * 128 + wm * 64 + mt * 16 + q * 4 + rg;
        C[(size_t)row * 3072 + col] = f2bf(acc[mt][nt][rg] + bias);
      }
  }
}

// ---------------- persistent bidirectional GRU ----------------
// 16 WGs: d = wg/8, isl = wg%8 owns h-cols [isl*64, isl*64+64).
// Waves 0-3: MFMA(K-lo) + cell + publish(hEx LLC) + flag + coalesced out store.
// Waves 4-7: gx distance-2 prefetch + MFMA(K-hi) + poll(2 peers) + gather.
// Release drain covers ONLY the 4 hEx stores (gx prefetch & out stores are
// owned by other waves / issued after the flag).
__launch_bounds__(512, 2)
__global__ void gru_kernel(const u16* gxAll, const u16* WhP, const float* b_f, const float* b_b,
                           u16* out_tmp, u16* hiddenA, uint32_t* hEx, int* flags) {
  __shared__ u16 hA[32 * 520];       // full h (bf16), row stride 520
  __shared__ float hOld[32 * 64];    // own slice, f32 master
  __shared__ float red[24 * 256];    // cross-wave K-half reduction
  __shared__ u16 gxs[3][32 * 192];   // triple-buffered gx slice [b][g][64]
  int wgid = blockIdx.x;
  int d = wgid >> 3, isl = wgid & 7;
  int tid = threadIdx.x;
  int wv = tid >> 6, lane = tid & 63;
  int a = wv & 3;      // n-tile quarter (16 h-cols)
  int jh = wv >> 2;    // K half
  int l15 = lane & 15, q = lane >> 4;

  for (int i = tid; i < 32 * 520 / 2; i += 512) ((uint32_t*)hA)[i] = 0u;
  for (int i = tid; i < 2048; i += 512) hOld[i] = 0.f;

  short8 Bf[3][8];
  for (int g = 0; g < 3; g++) {
    int ntg = g * 32 + isl * 4 + a;
    for (int kk = 0; kk < 8; kk++) {
      int kb = jh * 8 + kk;
      Bf[g][kk] = *(const short8*)(WhP + ((((size_t)d * 96 + ntg) * 16 + kb) * 64 + lane) * 8);
    }
  }
  const float* bias = d ? b_b : b_f;
  int cloc = a * 16 + l15;
  int gc = isl * 64 + cloc;
  float brz = bias[G3 + gc];
  float brr = bias[G3 + 512 + gc];
  float brn = bias[G3 + 1024 + gc];

  // prologue: stage gx for steps 0 and 1 into buffers 0,1
  for (int pb = 0; pb < 2; pb++) {
    int tp = d ? (TB - 1 - pb) : pb;
    for (int it = wv; it < 12; it += 8) {
      int slot = it * 64 + lane;
      int chunk = slot >> 3, sub = slot & 7;
      int b = chunk / 3, g = chunk - b * 3;
      gl_lds16(gxAll + (size_t)(b * TB + tp) * 3072 + d * 1536 + g * 512 + isl * 64 + sub * 8,
               (char*)gxs[pb] + it * 1024);
    }
  }
  __builtin_amdgcn_s_waitcnt(0);
  __syncthreads();

  for (int s = 0; s < TB; s++) {
    int t = d ? (TB - 1 - s) : s;
    int c0 = s % 3;
    // ---- phase A ----
    if (jh == 1 && s + 2 < TB) {  // gather waves: distance-2 gx prefetch
      int t2 = d ? (TB - 3 - s) : (s + 2);
      char* dst = (char*)gxs[(s + 2) % 3];
      for (int it = a * 3; it < a * 3 + 3; it++) {
        int slot = it * 64 + lane;
        int chunk = slot >> 3, sub = slot & 7;
        int b = chunk / 3, g = chunk - b * 3;
        gl_lds16(gxAll + (size_t)(b * TB + t2) * 3072 + d * 1536 + g * 512 + isl * 64 + sub * 8,
                 dst + it * 1024);
      }
    }
    fx4 acc[2][3];
    for (int mt = 0; mt < 2; mt++) for (int g = 0; g < 3; g++) acc[mt][g] = (fx4){0.f, 0.f, 0.f, 0.f};
    for (int mt = 0; mt < 2; mt++) {
      short8 Af[8];
      for (int kk = 0; kk < 8; kk++) {
        int kb = jh * 8 + kk;
        Af[kk] = *(const short8*)((const char*)hA + (mt * 16 + l15) * 1040 + kb * 64 + q * 16);
      }
      for (int g = 0; g < 3; g++)
        for (int kk = 0; kk < 8; kk++)
          acc[mt][g] = __builtin_amdgcn_mfma_f32_16x16x32_bf16(Af[kk], Bf[g][kk], acc[mt][g], 0, 0, 0);
    }
    if (jh == 1) {
      for (int mt = 0; mt < 2; mt++)
        for (int g = 0; g < 3; g++) {
          float* tp = red + ((a * 2 + mt) * 3 + g) * 256;
          for (int rg = 0; rg < 4; rg++) tp[(q * 4 + rg) * 16 + l15] = acc[mt][g][rg];
        }
    }
    __syncthreads();  // barrier 1

    // ---- phase B ----
    if (jh == 0) {  // cell + publish + flag + out store
      const u16* gxc = gxs[c0];
      u16 hv[2][4];
      for (int mt = 0; mt < 2; mt++) {
        const float* tpz = red + ((a * 2 + mt) * 3 + 0) * 256;
        const float* tpr = red + ((a * 2 + mt) * 3 + 1) * 256;
        const float* tpn = red + ((a * 2 + mt) * 3 + 2) * 256;
        for (int rg = 0; rg < 4; rg++) {
          int b = mt * 16 + q * 4 + rg;
          int fi = (q * 4 + rg) * 16 + l15;
          float ghz = acc[mt][0][rg] + tpz[fi] + brz;
          float ghr = acc[mt][1][rg] + tpr[fi] + brr;
          float ghn = acc[mt][2][rg] + tpn[fi] + brn;
          float gxz = bf2f(gxc[b * 192 + cloc]);
          float gxr = bf2f(gxc[b * 192 + 64 + cloc]);
          float gxn = bf2f(gxc[b * 192 + 128 + cloc]);
          float z = sigm(gxz + ghz);
          float rr = sigm(gxr + ghr);
          float hc = tanh_fast(gxn + rr * ghn);
          float hp = hOld[b * 64 + cloc];
          float hnw = z * hp + (1.f - z) * hc;
          hOld[b * 64 + cloc] = hnw;
          u16 hb = f2bf(hnw);
          hv[mt][rg] = hb;
          hA[b * 520 + gc] = hb;
        }
      }
      if (s < TB - 1) {
        int p = (s + 1) & 1;
        uint32_t* slot = hEx + ((size_t)(d * 2 + p) * 8 + isl) * 1024;
        for (int mt = 0; mt < 2; mt++)
          for (int pr = 0; pr < 2; pr++) {
            uint32_t pk = (uint32_t)hv[mt][2 * pr] | ((uint32_t)hv[mt][2 * pr + 1] << 16);
            __hip_atomic_store(&slot[cloc * 16 + mt * 8 + q * 2 + pr], pk,
                               __ATOMIC_RELAXED, __HIP_MEMORY_SCOPE_AGENT);
          }
      }
      __builtin_amdgcn_s_waitcnt(0);  // drains ONLY the 4 hEx stores
      if (s < TB - 1 && lane == 0)
        __hip_atomic_fetch_add(&flags[wgid * 64], 1, __ATOMIC_RELAXED, __HIP_MEMORY_SCOPE_AGENT);
      // coalesced output store, AFTER the flag (off critical path)
      u16* outp = out_tmp + ((size_t)(d * 8 + isl) * 512 + t) * 2048;
      for (int mt = 0; mt < 2; mt++)
        for (int rg = 0; rg < 4; rg++)
          outp[(mt * 16 + q * 4 + rg) * 64 + cloc] = hv[mt][rg];
      if (s == TB - 1)
        for (int mt = 0; mt < 2; mt++)
          for (int rg = 0; rg < 4; rg++)
            hiddenA[(size_t)(mt * 16 + q * 4 + rg) * 1024 + d * 512 + gc] = hv[mt][rg];
    } else if (s < TB - 1) {  // gather waves: poll + gather 2 peers
      int p = (s + 1) & 1;
      int target = 4 * (s + 1);
      for (int pi = 0; pi < 2; pi++) {
        int po = a + 1 + pi * 4;
        if (po > 7) break;
        int pj = (isl + po) & 7;
        int peer = d * 8 + pj;
        long long spins = 0;
        while (__hip_atomic_load(&flags[peer * 64], __ATOMIC_RELAXED, __HIP_MEMORY_SCOPE_AGENT) < target) {
          if (++spins > (1LL << 40)) break;
        }
        const uint32_t* src = hEx + ((size_t)(d * 2 + p) * 8 + pj) * 1024 + lane * 16;
        uint32_t v[16];
        for (int k = 0; k < 16; k++)
          v[k] = __hip_atomic_load(&src[k], __ATOMIC_RELAXED, __HIP_MEMORY_SCOPE_AGENT);
        for (int k = 0; k < 16; k++) {
          int mt = k >> 3, rem = k & 7;
          int row0 = mt * 16 + (rem >> 1) * 4 + (rem & 1) * 2;
          hA[row0 * 520 + pj * 64 + lane] = (u16)(v[k] & 0xffffu);
          hA[(row0 + 1) * 520 + pj * 64 + lane] = (u16)(v[k] >> 16);
        }
      }
    }
    __syncthreads();  // barrier 2
  }
}

// ---------------- projection: [out_f|out_b] @ Wd + bd ----------------
// A rows (tm<128) come from permuted out_tmp[d][isl][t][b][64].
__launch_bounds__(256)
__global__ void gemm_proj(const u16* Aall, const u16* hiddenA, const u16* WdT,
                          const float* bd, float* out) {
  __shared__ u16 As[128 * 32];
  __shared__ u16 Bs[128 * 32];
  int tn = blockIdx.x, tm = blockIdx.y;
  int b0 = tm >> 2, tbase = (tm & 3) * 128;
  int tid = threadIdx.x, wv = tid >> 6, lane = tid & 63;
  int wm = wv >> 1, wn = wv & 1;
  int l15 = lane & 15, q = lane >> 4;
  fx4 acc[4][4];
  for (int i = 0; i < 4; i++) for (int jn = 0; jn < 4; jn++) acc[i][jn] = (fx4){0.f, 0.f, 0.f, 0.f};
  for (int kk = 0; kk < 32; kk++) {
    for (int cc = 0; cc < 2; cc++) {
      int row = wv * 32 + cc * 16 + (lane >> 2);
      int seg = lane & 3;
      int k = kk * 32 + seg * 8;
      const u16* ap;
      if (tm < 128) {
        int d2 = k >> 9, isl2 = (k >> 6) & 7, c = k & 63;
        ap = Aall + ((size_t)((d2 * 8 + isl2) * 512) + tbase + row) * 2048 + b0 * 64 + c;
      } else {
        ap = hiddenA + (size_t)row * 1024 + k;
      }
      gl_lds16(ap, (char*)As + (wv * 32 + cc * 16) * 64);
      gl_lds16(WdT + (size_t)(tn * 128 + row) * 1024 + k,
               (char*)Bs + (wv * 32 + cc * 16) * 64);
    }
    __builtin_amdgcn_s_waitcnt(0);
    __syncthreads();
    short8 af[4], bfr[4];
    for (int mt = 0; mt < 4; mt++)
      af[mt] = *(const short8*)((const char*)As + (wm * 64 + mt * 16 + l15) * 64 + q * 16);
    for (int nt = 0; nt < 4; nt++)
      bfr[nt] = *(const short8*)((const char*)Bs + (wn * 64 + nt * 16 + l15) * 64 + q * 16);
    for (int mt = 0; mt < 4; mt++)
      for (int nt = 0; nt < 4; nt++)
        acc[mt][nt] = __builtin_amdgcn_mfma_f32_16x16x32_bf16(af[mt], bfr[nt], acc[mt][nt], 0, 0, 0);
    __syncthreads();
  }
  for (int nt = 0; nt < 4; nt++) {
    int col = tn * 128 + wn * 64 + nt * 16 + l15;
    float bias = bd[col];
    for (int mt = 0; mt < 4; mt++)
      for (int rg = 0; rg < 4; rg++) {
        int row = wm * 64 + mt * 16 + q * 4 + rg;
        float v = acc[mt][nt][rg] + bias;
        if (tm < 128) out[((size_t)tm * 128 + row) * 512 + col] = v;
        else if (row < 32) out[(size_t)16384 * 512 + (size_t)row * 512 + col] = v;
      }
  }
}

extern "C" void kernel_launch(void* const* d_in, const int* in_sizes, int n_in,
                              void* d_out, int out_size, void* d_ws, size_t ws_size,
                              hipStream_t stream) {
  (void)in_sizes; (void)n_in; (void)out_size; (void)ws_size;
  const int* seqs = (const int*)d_in[0];
  const float* emb = (const float*)d_in[2];
  const float* Wx_f = (const float*)d_in[3];
  const float* Wh_f = (const float*)d_in[4];
  const float* b_f = (const float*)d_in[5];
  const float* Wx_b = (const float*)d_in[6];
  const float* Wh_b = (const float*)d_in[7];
  const float* b_b = (const float*)d_in[8];
  const float* Wd = (const float*)d_in[9];
  const float* bd = (const float*)d_in[10];
  char* ws = (char*)d_ws;
  u16* WxcT     = (u16*)(ws + 0);
  u16* WhP      = (u16*)(ws + 3145728);
  u16* WdT      = (u16*)(ws + 6291456);
  u16* embedded = (u16*)(ws + 7340032);
  u16* gxAll    = (u16*)(ws + 24117248);
  u16* out_tmp  = (u16*)(ws + 124780544);
  u16* hiddenA  = (u16*)(ws + 158334976);
  uint32_t* hEx = (uint32_t*)(ws + 158597120);
  int* flags    = (int*)(ws + 158728192);  // 16 WGs x 256B lines

  hipMemsetAsync(flags, 0, 16 * 64 * sizeof(int), stream);
  prep_kernel<<<512, 256, 0, stream>>>(Wx_f, Wh_f, Wx_b, Wh_b, Wd, WxcT, WhP, WdT);
  embed_kernel<<<16384, 128, 0, stream>>>(seqs, emb, embedded);
  gemm_gx<<<dim3(24, 128), 256, 0, stream>>>(embedded, WxcT, b_f, b_b, gxAll);
  gru_kernel<<<16, 512, 0, stream>>>(gxAll, WhP, b_f, b_b, out_tmp, hiddenA, hEx, flags);
  gemm_proj<<<dim3(4, 129), 256, 0, stream>>>(out_tmp, hiddenA, WdT, bd, (float*)d_out);
}